// Round 5
// baseline (370.097 us; speedup 1.0000x reference)
//
#include <hip/hip_runtime.h>
#include <hip/hip_bf16.h>

#define NN 16384
#define TT 4
#define HH 64
#define NT (NN * TT)
#define NEG_SLOPE 0.2f
#define LN_EPS 1e-5f

using bf16 = __hip_bfloat16;

__device__ __forceinline__ float bf2f(unsigned short u) {
    return __uint_as_float((unsigned)u << 16);
}

// ---------------- CSR build (both edge sets fused) ----------------

__global__ void zero_kernel(int* __restrict__ a, int n) {
    int i = blockIdx.x * blockDim.x + threadIdx.x;
    if (i < n) a[i] = 0;
}

__global__ void hist2_kernel(const int* __restrict__ dst_s, const int* __restrict__ dst_f,
                             int* __restrict__ cnt2, int E) {
    int e = blockIdx.x * blockDim.x + threadIdx.x;
    if (e < E) {
        atomicAdd(&cnt2[dst_s[e]], 1);
    } else {
        e -= E;
        if (e < E) atomicAdd(&cnt2[NN + dst_f[e]], 1);
    }
}

__global__ __launch_bounds__(1024) void scan2_kernel(const int* __restrict__ cnt2,
                                                     int* __restrict__ rp2,
                                                     int* __restrict__ cur2) {
    __shared__ int part[1024];
    const int set = blockIdx.x;
    const int* cnt = cnt2 + set * NN;
    int* rp = rp2 + set * (NN + 1);
    int* cur = cur2 + set * NN;
    int tid = threadIdx.x;
    int base = tid * 16;
    int local[16];
    int sum = 0;
#pragma unroll
    for (int i = 0; i < 16; i++) { local[i] = cnt[base + i]; sum += local[i]; }
    part[tid] = sum;
    __syncthreads();
    for (int off = 1; off < 1024; off <<= 1) {
        int v = (tid >= off) ? part[tid - off] : 0;
        __syncthreads();
        part[tid] += v;
        __syncthreads();
    }
    int run = (tid == 0) ? 0 : part[tid - 1];
#pragma unroll
    for (int i = 0; i < 16; i++) {
        rp[base + i] = run;
        cur[base + i] = run;
        run += local[i];
    }
    if (tid == 1023) rp[NN] = run;
}

__global__ void scatter2_kernel(const int* __restrict__ ei_s, const int* __restrict__ ei_f,
                                int* __restrict__ cur2, int* __restrict__ col2, int E) {
    int e = blockIdx.x * blockDim.x + threadIdx.x;
    if (e < E) {
        int d = ei_s[E + e];
        int pos = atomicAdd(&cur2[d], 1);
        col2[pos] = ei_s[e];
    } else {
        e -= E;
        if (e < E) {
            int d = ei_f[E + e];
            int pos = atomicAdd(&cur2[NN + d], 1);
            col2[E + pos] = ei_f[e];
        }
    }
}

// ------- fused dual transform: h_s = x*Ws, h_f = x*Wf, scores with lrelu ------
// Block = 256 thr (4 waves), 128 rows/block. x tile staged in LDS; the GEMV
// inner loop reads x via SAME-ADDRESS float4 LDS broadcasts (conflict-free),
// W columns in VGPRs. 2 rows in flight -> 4 independent FMA chains.

__global__ __launch_bounds__(256) void transform2_kernel(
    const float4* __restrict__ x4,
    const float* __restrict__ Ws, const float* __restrict__ as_,
    const float* __restrict__ Wf, const float* __restrict__ af,
    bf16* __restrict__ h_s, float* __restrict__ sc_s,
    bf16* __restrict__ h_f, float* __restrict__ sc_f) {
    __shared__ float4 xs4[128 * 16];  // 128 rows x 64 floats = 32 KB
    const int tid = threadIdx.x;
    const int lane = tid & 63;
    const int wv = tid >> 6;
    float Wsreg[64], Wfreg[64];
#pragma unroll
    for (int k = 0; k < 64; k++) Wsreg[k] = Ws[k * 64 + lane];
#pragma unroll
    for (int k = 0; k < 64; k++) Wfreg[k] = Wf[k * 64 + lane];
    const float avs = as_[lane];
    const float avf = af[lane];
    const int row0 = blockIdx.x * 128;
    // stage 128 rows (2048 float4), coalesced 16B/lane
#pragma unroll
    for (int i = 0; i < 8; i++) {
        int f = tid + i * 256;
        xs4[f] = x4[(long)row0 * 16 + f];
    }
    __syncthreads();
    for (int rr = 0; rr < 32; rr += 2) {
        const int ra = wv * 32 + rr;
        const int rb = ra + 1;
        float asa = 0.f, afa = 0.f, asb = 0.f, afb = 0.f;
#pragma unroll
        for (int k4 = 0; k4 < 16; k4++) {
            float4 xa = xs4[ra * 16 + k4];  // broadcast read
            float4 xb = xs4[rb * 16 + k4];  // broadcast read
            asa = fmaf(xa.x, Wsreg[4 * k4 + 0], asa);
            asa = fmaf(xa.y, Wsreg[4 * k4 + 1], asa);
            asa = fmaf(xa.z, Wsreg[4 * k4 + 2], asa);
            asa = fmaf(xa.w, Wsreg[4 * k4 + 3], asa);
            afa = fmaf(xa.x, Wfreg[4 * k4 + 0], afa);
            afa = fmaf(xa.y, Wfreg[4 * k4 + 1], afa);
            afa = fmaf(xa.z, Wfreg[4 * k4 + 2], afa);
            afa = fmaf(xa.w, Wfreg[4 * k4 + 3], afa);
            asb = fmaf(xb.x, Wsreg[4 * k4 + 0], asb);
            asb = fmaf(xb.y, Wsreg[4 * k4 + 1], asb);
            asb = fmaf(xb.z, Wsreg[4 * k4 + 2], asb);
            asb = fmaf(xb.w, Wsreg[4 * k4 + 3], asb);
            afb = fmaf(xb.x, Wfreg[4 * k4 + 0], afb);
            afb = fmaf(xb.y, Wfreg[4 * k4 + 1], afb);
            afb = fmaf(xb.z, Wfreg[4 * k4 + 2], afb);
            afb = fmaf(xb.w, Wfreg[4 * k4 + 3], afb);
        }
        const long ga = (long)(row0 + ra) * 64 + lane;
        const long gb = (long)(row0 + rb) * 64 + lane;
        h_s[ga] = __float2bfloat16(asa);
        h_f[ga] = __float2bfloat16(afa);
        h_s[gb] = __float2bfloat16(asb);
        h_f[gb] = __float2bfloat16(afb);
        // score reductions: 4 independent chains interleave
        float vsa = asa * avs, vfa = afa * avf, vsb = asb * avs, vfb = afb * avf;
#pragma unroll
        for (int off = 32; off > 0; off >>= 1) {
            vsa += __shfl_xor(vsa, off, 64);
            vfa += __shfl_xor(vfa, off, 64);
            vsb += __shfl_xor(vsb, off, 64);
            vfb += __shfl_xor(vfb, off, 64);
        }
        if (lane == 0) {
            sc_s[row0 + ra] = (vsa > 0.f) ? vsa : NEG_SLOPE * vsa;
            sc_f[row0 + ra] = (vfa > 0.f) ? vfa : NEG_SLOPE * vfa;
            sc_s[row0 + rb] = (vsb > 0.f) ? vsb : NEG_SLOPE * vsb;
            sc_f[row0 + rb] = (vfb > 0.f) ? vfb : NEG_SLOPE * vfb;
        }
    }
}

// ---------------- attention aggregation ----------------
// wave per node; lane: t = lane>>4, channels 4*(lane&15)..+3.
// single-pass softmax (logits O(+-8): no overflow; identical to max-subtracted).

__device__ __forceinline__ void agg_set(const ushort4* __restrict__ h4,
                                        const float* __restrict__ sc,
                                        const int* __restrict__ rp,
                                        const int* __restrict__ col,
                                        int n, int t, int lane, float4& msg) {
    const int beg = rp[n], end = rp[n + 1];
    float den = 0.f;
    float ax = 0.f, ay = 0.f, az = 0.f, aw = 0.f;
    int j = beg;
    for (; j + 8 <= end; j += 8) {
        int s[8];
        float l[8];
        ushort4 hh[8];
#pragma unroll
        for (int u = 0; u < 8; u++) s[u] = col[j + u];
#pragma unroll
        for (int u = 0; u < 8; u++) l[u] = sc[s[u] * 4 + t];
#pragma unroll
        for (int u = 0; u < 8; u++) hh[u] = h4[s[u] * 64 + lane];
#pragma unroll
        for (int u = 0; u < 8; u++) {
            float e = __expf(l[u]);
            den += e;
            ax = fmaf(e, bf2f(hh[u].x), ax);
            ay = fmaf(e, bf2f(hh[u].y), ay);
            az = fmaf(e, bf2f(hh[u].z), az);
            aw = fmaf(e, bf2f(hh[u].w), aw);
        }
    }
    for (; j + 4 <= end; j += 4) {
        int s[4];
        float l[4];
        ushort4 hh[4];
#pragma unroll
        for (int u = 0; u < 4; u++) s[u] = col[j + u];
#pragma unroll
        for (int u = 0; u < 4; u++) l[u] = sc[s[u] * 4 + t];
#pragma unroll
        for (int u = 0; u < 4; u++) hh[u] = h4[s[u] * 64 + lane];
#pragma unroll
        for (int u = 0; u < 4; u++) {
            float e = __expf(l[u]);
            den += e;
            ax = fmaf(e, bf2f(hh[u].x), ax);
            ay = fmaf(e, bf2f(hh[u].y), ay);
            az = fmaf(e, bf2f(hh[u].z), az);
            aw = fmaf(e, bf2f(hh[u].w), aw);
        }
    }
    for (; j < end; j++) {
        int s0 = col[j];
        float l0 = sc[s0 * 4 + t];
        ushort4 h0 = h4[s0 * 64 + lane];
        float e0 = __expf(l0);
        den += e0;
        ax = fmaf(e0, bf2f(h0.x), ax);
        ay = fmaf(e0, bf2f(h0.y), ay);
        az = fmaf(e0, bf2f(h0.z), az);
        aw = fmaf(e0, bf2f(h0.w), aw);
    }
    if (end > beg) {
        float r = 1.f / den;
        msg.x = ax * r; msg.y = ay * r; msg.z = az * r; msg.w = aw * r;
    } else {
        msg.x = msg.y = msg.z = msg.w = 0.f;
    }
}

__global__ __launch_bounds__(256) void aggregate_kernel(
    const float4* __restrict__ x4,
    const ushort4* __restrict__ hs4, const float* __restrict__ scs,
    const int* __restrict__ rps, const int* __restrict__ cols,
    const ushort4* __restrict__ hf4, const float* __restrict__ scf,
    const int* __restrict__ rpf, const int* __restrict__ colf,
    const float4* __restrict__ g4, const float4* __restrict__ b4,
    float4* __restrict__ out4) {
    const int wv = threadIdx.x >> 6;
    const int lane = threadIdx.x & 63;
    const int n = blockIdx.x * 4 + wv;
    const int t = lane >> 4;
    const int ci = lane & 15;

    float4 xv = x4[n * 64 + lane];  // x[n][t][4*ci..+3]

    float4 ms, mf;
    agg_set(hs4, scs, rps, cols, n, t, lane, ms);
    agg_set(hf4, scf, rpf, colf, n, t, lane, mf);

    float v0 = xv.x + 0.5f * (ms.x + mf.x);
    float v1 = xv.y + 0.5f * (ms.y + mf.y);
    float v2 = xv.z + 0.5f * (ms.z + mf.z);
    float v3 = xv.w + 0.5f * (ms.w + mf.w);

    // LayerNorm over H=64: 16-lane group (same t), 4 values/lane
    float sum = (v0 + v1) + (v2 + v3);
#pragma unroll
    for (int off = 1; off < 16; off <<= 1) sum += __shfl_xor(sum, off, 64);
    float mu = sum * (1.f / 64.f);
    float d0 = v0 - mu, d1 = v1 - mu, d2 = v2 - mu, d3 = v3 - mu;
    float var = (d0 * d0 + d1 * d1) + (d2 * d2 + d3 * d3);
#pragma unroll
    for (int off = 1; off < 16; off <<= 1) var += __shfl_xor(var, off, 64);
    var *= (1.f / 64.f);
    float inv = rsqrtf(var + LN_EPS);
    float4 gv = g4[ci], bv = b4[ci];
    float4 o;
    o.x = d0 * inv * gv.x + bv.x;
    o.y = d1 * inv * gv.y + bv.y;
    o.z = d2 * inv * gv.z + bv.z;
    o.w = d3 * inv * gv.w + bv.w;
    out4[n * 64 + lane] = o;
}

// ---------------- launch ----------------

extern "C" void kernel_launch(void* const* d_in, const int* in_sizes, int n_in,
                              void* d_out, int out_size, void* d_ws, size_t ws_size,
                              hipStream_t stream) {
    const float* pred = (const float*)d_in[0];
    const int* ei_s = (const int*)d_in[1];
    const int* ei_f = (const int*)d_in[2];
    const float* W0s = (const float*)d_in[3];
    const float* a0s = (const float*)d_in[4];
    const float* W0f = (const float*)d_in[5];
    const float* a0f = (const float*)d_in[6];
    const float* g0  = (const float*)d_in[7];
    const float* b0  = (const float*)d_in[8];
    const float* W1s = (const float*)d_in[9];
    const float* a1s = (const float*)d_in[10];
    const float* W1f = (const float*)d_in[11];
    const float* a1f = (const float*)d_in[12];
    const float* g1  = (const float*)d_in[13];
    const float* b1  = (const float*)d_in[14];
    const int E = in_sizes[1] / 2;  // 262144

    // workspace bump allocator (~37 MB)
    char* ws = (char*)d_ws;
    auto alloc = [&](size_t bytes) {
        char* p = ws;
        ws += (bytes + 255) & ~(size_t)255;
        return p;
    };
    int* cnt2 = (int*)alloc((size_t)2 * NN * sizeof(int));
    int* rp2  = (int*)alloc((size_t)2 * (NN + 1) * sizeof(int));
    int* cur2 = (int*)alloc((size_t)2 * NN * sizeof(int));
    int* col2 = (int*)alloc((size_t)2 * E * sizeof(int));
    bf16* h_s = (bf16*)alloc((size_t)NT * HH * sizeof(bf16));
    bf16* h_f = (bf16*)alloc((size_t)NT * HH * sizeof(bf16));
    float* sc_s = (float*)alloc((size_t)NT * sizeof(float));
    float* sc_f = (float*)alloc((size_t)NT * sizeof(float));
    float* x_mid = (float*)alloc((size_t)NT * HH * sizeof(float));

    const int* rp_s = rp2;
    const int* rp_f = rp2 + (NN + 1);
    const int* col_s = col2;
    const int* col_f = col2 + E;

    const int EB = (E + 255) / 256;

    // CSR build (both edge sets in each launch)
    zero_kernel<<<(2 * NN) / 256, 256, 0, stream>>>(cnt2, 2 * NN);
    hist2_kernel<<<2 * EB, 256, 0, stream>>>(ei_s + E, ei_f + E, cnt2, E);
    scan2_kernel<<<2, 1024, 0, stream>>>(cnt2, rp2, cur2);
    scatter2_kernel<<<2 * EB, 256, 0, stream>>>(ei_s, ei_f, cur2, col2, E);

    // layer 0
    transform2_kernel<<<NT / 128, 256, 0, stream>>>(
        (const float4*)pred, W0s, a0s, W0f, a0f, h_s, sc_s, h_f, sc_f);
    aggregate_kernel<<<NN / 4, 256, 0, stream>>>(
        (const float4*)pred, (const ushort4*)h_s, sc_s, rp_s, col_s,
        (const ushort4*)h_f, sc_f, rp_f, col_f,
        (const float4*)g0, (const float4*)b0, (float4*)x_mid);

    // layer 1
    transform2_kernel<<<NT / 128, 256, 0, stream>>>(
        (const float4*)x_mid, W1s, a1s, W1f, a1f, h_s, sc_s, h_f, sc_f);
    aggregate_kernel<<<NN / 4, 256, 0, stream>>>(
        (const float4*)x_mid, (const ushort4*)h_s, sc_s, rp_s, col_s,
        (const ushort4*)h_f, sc_f, rp_f, col_f,
        (const float4*)g1, (const float4*)b1, (float4*)d_out);
}

// Round 6
// 256.044 us; speedup vs baseline: 1.4454x; 1.4454x over previous
//
#include <hip/hip_runtime.h>
#include <hip/hip_bf16.h>

#define NN 16384
#define TT 4
#define HH 64
#define NT (NN * TT)
#define NEG_SLOPE 0.2f
#define LN_EPS 1e-5f

typedef __attribute__((ext_vector_type(8))) short short8;   // 8 bf16 (4 VGPRs)
typedef __attribute__((ext_vector_type(4))) float f32x4;    // MFMA accumulator

__device__ __forceinline__ float bf2f(unsigned short u) {
    return __uint_as_float((unsigned)u << 16);
}
// f32 -> bf16 RNE, layout-independent
__device__ __forceinline__ unsigned short f2bf(float f) {
    unsigned u = __float_as_uint(f);
    return (unsigned short)((u + 0x7FFF + ((u >> 16) & 1)) >> 16);
}

// ---------------- CSR build (both edge sets fused) ----------------

__global__ void zero_kernel(int* __restrict__ a, int n) {
    int i = blockIdx.x * blockDim.x + threadIdx.x;
    if (i < n) a[i] = 0;
}

__global__ void hist2_kernel(const int* __restrict__ dst_s, const int* __restrict__ dst_f,
                             int* __restrict__ cnt2, int E) {
    int e = blockIdx.x * blockDim.x + threadIdx.x;
    if (e < E) {
        atomicAdd(&cnt2[dst_s[e]], 1);
    } else {
        e -= E;
        if (e < E) atomicAdd(&cnt2[NN + dst_f[e]], 1);
    }
}

__global__ __launch_bounds__(1024) void scan2_kernel(const int* __restrict__ cnt2,
                                                     int* __restrict__ rp2,
                                                     int* __restrict__ cur2) {
    __shared__ int part[1024];
    const int set = blockIdx.x;
    const int* cnt = cnt2 + set * NN;
    int* rp = rp2 + set * (NN + 1);
    int* cur = cur2 + set * NN;
    int tid = threadIdx.x;
    int base = tid * 16;
    int local[16];
    int sum = 0;
#pragma unroll
    for (int i = 0; i < 16; i++) { local[i] = cnt[base + i]; sum += local[i]; }
    part[tid] = sum;
    __syncthreads();
    for (int off = 1; off < 1024; off <<= 1) {
        int v = (tid >= off) ? part[tid - off] : 0;
        __syncthreads();
        part[tid] += v;
        __syncthreads();
    }
    int run = (tid == 0) ? 0 : part[tid - 1];
#pragma unroll
    for (int i = 0; i < 16; i++) {
        rp[base + i] = run;
        cur[base + i] = run;
        run += local[i];
    }
    if (tid == 1023) rp[NN] = run;
}

__global__ void scatter2_kernel(const int* __restrict__ ei_s, const int* __restrict__ ei_f,
                                int* __restrict__ cur2, int* __restrict__ col2, int E) {
    int e = blockIdx.x * blockDim.x + threadIdx.x;
    if (e < E) {
        int d = ei_s[E + e];
        int pos = atomicAdd(&cur2[d], 1);
        col2[pos] = ei_s[e];
    } else {
        e -= E;
        if (e < E) {
            int d = ei_f[E + e];
            int pos = atomicAdd(&cur2[NN + d], 1);
            col2[E + pos] = ei_f[e];
        }
    }
}

// ------- fused dual transform via MFMA: h_s = x*Ws, h_f = x*Wf + scores ------
// v_mfma_f32_16x16x32_bf16. A-frag: A[m=lane&15][k=quad*8+j] (j=elem idx).
// B-frag (K x N): B[k=quad*8+j][n=lane&15]. C/D: col=lane&15, row=quad*4+reg.
// Wave = 32 rows (2 row-tiles); block = 4 waves = 128 rows; grid = NT/128.

__global__ __launch_bounds__(256) void transform2_kernel(
    const float4* __restrict__ x4,
    const float* __restrict__ Ws, const float* __restrict__ as_,
    const float* __restrict__ Wf, const float* __restrict__ af,
    unsigned short* __restrict__ h_s, float* __restrict__ sc_s,
    unsigned short* __restrict__ h_f, float* __restrict__ sc_f) {
    const int lane = threadIdx.x & 63;
    const int wv = threadIdx.x >> 6;
    const int m = lane & 15;
    const int quad = lane >> 4;

    // B-frags: [col-tile c][K-step ks]; W[k][n] at Ws[k*64 + c*16+m]
    short8 Bs[4][2], Bf[4][2];
#pragma unroll
    for (int c = 0; c < 4; c++) {
#pragma unroll
        for (int ks = 0; ks < 2; ks++) {
#pragma unroll
            for (int j = 0; j < 8; j++) {
                int k = ks * 32 + quad * 8 + j;
                int n = c * 16 + m;
                Bs[c][ks][j] = (short)f2bf(Ws[k * 64 + n]);
                Bf[c][ks][j] = (short)f2bf(Wf[k * 64 + n]);
            }
        }
    }
    float a_s[4], a_f[4];
#pragma unroll
    for (int c = 0; c < 4; c++) { a_s[c] = as_[c * 16 + m]; a_f[c] = af[c * 16 + m]; }

    const int rowbase = blockIdx.x * 128 + wv * 32;
#pragma unroll
    for (int rt = 0; rt < 2; rt++) {
        const int row0 = rowbase + rt * 16;
        // A-frags: x[row0+m][quad*8..+7] (K 0..31) and +32 (K 32..63)
        const long xbase = (long)(row0 + m) * 16 + quad * 2;
        float4 xa = x4[xbase];
        float4 xb = x4[xbase + 1];
        float4 xc = x4[xbase + 8];
        float4 xd = x4[xbase + 9];
        short8 A0, A1;
        A0[0] = (short)f2bf(xa.x); A0[1] = (short)f2bf(xa.y);
        A0[2] = (short)f2bf(xa.z); A0[3] = (short)f2bf(xa.w);
        A0[4] = (short)f2bf(xb.x); A0[5] = (short)f2bf(xb.y);
        A0[6] = (short)f2bf(xb.z); A0[7] = (short)f2bf(xb.w);
        A1[0] = (short)f2bf(xc.x); A1[1] = (short)f2bf(xc.y);
        A1[2] = (short)f2bf(xc.z); A1[3] = (short)f2bf(xc.w);
        A1[4] = (short)f2bf(xd.x); A1[5] = (short)f2bf(xd.y);
        A1[6] = (short)f2bf(xd.z); A1[7] = (short)f2bf(xd.w);

        f32x4 accs[4], accf[4];
#pragma unroll
        for (int c = 0; c < 4; c++) {
            accs[c] = (f32x4){0.f, 0.f, 0.f, 0.f};
            accf[c] = (f32x4){0.f, 0.f, 0.f, 0.f};
        }
#pragma unroll
        for (int c = 0; c < 4; c++) {
            accs[c] = __builtin_amdgcn_mfma_f32_16x16x32_bf16(A0, Bs[c][0], accs[c], 0, 0, 0);
            accs[c] = __builtin_amdgcn_mfma_f32_16x16x32_bf16(A1, Bs[c][1], accs[c], 0, 0, 0);
            accf[c] = __builtin_amdgcn_mfma_f32_16x16x32_bf16(A0, Bf[c][0], accf[c], 0, 0, 0);
            accf[c] = __builtin_amdgcn_mfma_f32_16x16x32_bf16(A1, Bf[c][1], accf[c], 0, 0, 0);
        }
        // store h (bf16) + per-row scores from f32 accumulators
#pragma unroll
        for (int reg = 0; reg < 4; reg++) {
            const int row = row0 + quad * 4 + reg;
            float ps = 0.f, pf = 0.f;
#pragma unroll
            for (int c = 0; c < 4; c++) {
                h_s[(long)row * 64 + c * 16 + m] = f2bf(accs[c][reg]);
                h_f[(long)row * 64 + c * 16 + m] = f2bf(accf[c][reg]);
                ps = fmaf(accs[c][reg], a_s[c], ps);
                pf = fmaf(accf[c][reg], a_f[c], pf);
            }
#pragma unroll
            for (int off = 1; off < 16; off <<= 1) {
                ps += __shfl_xor(ps, off, 64);
                pf += __shfl_xor(pf, off, 64);
            }
            if (m == 0) {
                sc_s[row] = (ps > 0.f) ? ps : NEG_SLOPE * ps;  // LeakyReLU folded in
                sc_f[row] = (pf > 0.f) ? pf : NEG_SLOPE * pf;
            }
        }
    }
}

// ---------------- attention aggregation ----------------
// wave per node; lane: t = lane>>4, channels 4*(lane&15)..+3.
// single-pass softmax (logits O(+-8): no overflow; identical to max-subtracted).

__device__ __forceinline__ void agg_set(const ushort4* __restrict__ h4,
                                        const float* __restrict__ sc,
                                        const int* __restrict__ rp,
                                        const int* __restrict__ col,
                                        int n, int t, int lane, float4& msg) {
    const int beg = rp[n], end = rp[n + 1];
    float den = 0.f;
    float ax = 0.f, ay = 0.f, az = 0.f, aw = 0.f;
    int j = beg;
    for (; j + 8 <= end; j += 8) {
        int s[8];
        float l[8];
        ushort4 hh[8];
#pragma unroll
        for (int u = 0; u < 8; u++) s[u] = col[j + u];
#pragma unroll
        for (int u = 0; u < 8; u++) l[u] = sc[s[u] * 4 + t];
#pragma unroll
        for (int u = 0; u < 8; u++) hh[u] = h4[s[u] * 64 + lane];
#pragma unroll
        for (int u = 0; u < 8; u++) {
            float e = __expf(l[u]);
            den += e;
            ax = fmaf(e, bf2f(hh[u].x), ax);
            ay = fmaf(e, bf2f(hh[u].y), ay);
            az = fmaf(e, bf2f(hh[u].z), az);
            aw = fmaf(e, bf2f(hh[u].w), aw);
        }
    }
    for (; j + 4 <= end; j += 4) {
        int s[4];
        float l[4];
        ushort4 hh[4];
#pragma unroll
        for (int u = 0; u < 4; u++) s[u] = col[j + u];
#pragma unroll
        for (int u = 0; u < 4; u++) l[u] = sc[s[u] * 4 + t];
#pragma unroll
        for (int u = 0; u < 4; u++) hh[u] = h4[s[u] * 64 + lane];
#pragma unroll
        for (int u = 0; u < 4; u++) {
            float e = __expf(l[u]);
            den += e;
            ax = fmaf(e, bf2f(hh[u].x), ax);
            ay = fmaf(e, bf2f(hh[u].y), ay);
            az = fmaf(e, bf2f(hh[u].z), az);
            aw = fmaf(e, bf2f(hh[u].w), aw);
        }
    }
    for (; j < end; j++) {
        int s0 = col[j];
        float l0 = sc[s0 * 4 + t];
        ushort4 h0 = h4[s0 * 64 + lane];
        float e0 = __expf(l0);
        den += e0;
        ax = fmaf(e0, bf2f(h0.x), ax);
        ay = fmaf(e0, bf2f(h0.y), ay);
        az = fmaf(e0, bf2f(h0.z), az);
        aw = fmaf(e0, bf2f(h0.w), aw);
    }
    if (end > beg) {
        float r = 1.f / den;
        msg.x = ax * r; msg.y = ay * r; msg.z = az * r; msg.w = aw * r;
    } else {
        msg.x = msg.y = msg.z = msg.w = 0.f;
    }
}

__global__ __launch_bounds__(256) void aggregate_kernel(
    const float4* __restrict__ x4,
    const ushort4* __restrict__ hs4, const float* __restrict__ scs,
    const int* __restrict__ rps, const int* __restrict__ cols,
    const ushort4* __restrict__ hf4, const float* __restrict__ scf,
    const int* __restrict__ rpf, const int* __restrict__ colf,
    const float4* __restrict__ g4, const float4* __restrict__ b4,
    float4* __restrict__ out4) {
    const int wv = threadIdx.x >> 6;
    const int lane = threadIdx.x & 63;
    const int n = blockIdx.x * 4 + wv;
    const int t = lane >> 4;
    const int ci = lane & 15;

    float4 xv = x4[n * 64 + lane];  // x[n][t][4*ci..+3]

    float4 ms, mf;
    agg_set(hs4, scs, rps, cols, n, t, lane, ms);
    agg_set(hf4, scf, rpf, colf, n, t, lane, mf);

    float v0 = xv.x + 0.5f * (ms.x + mf.x);
    float v1 = xv.y + 0.5f * (ms.y + mf.y);
    float v2 = xv.z + 0.5f * (ms.z + mf.z);
    float v3 = xv.w + 0.5f * (ms.w + mf.w);

    // LayerNorm over H=64: 16-lane group (same t), 4 values/lane
    float sum = (v0 + v1) + (v2 + v3);
#pragma unroll
    for (int off = 1; off < 16; off <<= 1) sum += __shfl_xor(sum, off, 64);
    float mu = sum * (1.f / 64.f);
    float d0 = v0 - mu, d1 = v1 - mu, d2 = v2 - mu, d3 = v3 - mu;
    float var = (d0 * d0 + d1 * d1) + (d2 * d2 + d3 * d3);
#pragma unroll
    for (int off = 1; off < 16; off <<= 1) var += __shfl_xor(var, off, 64);
    var *= (1.f / 64.f);
    float inv = rsqrtf(var + LN_EPS);
    float4 gv = g4[ci], bv = b4[ci];
    float4 o;
    o.x = d0 * inv * gv.x + bv.x;
    o.y = d1 * inv * gv.y + bv.y;
    o.z = d2 * inv * gv.z + bv.z;
    o.w = d3 * inv * gv.w + bv.w;
    out4[n * 64 + lane] = o;
}

// ---------------- launch ----------------

extern "C" void kernel_launch(void* const* d_in, const int* in_sizes, int n_in,
                              void* d_out, int out_size, void* d_ws, size_t ws_size,
                              hipStream_t stream) {
    const float* pred = (const float*)d_in[0];
    const int* ei_s = (const int*)d_in[1];
    const int* ei_f = (const int*)d_in[2];
    const float* W0s = (const float*)d_in[3];
    const float* a0s = (const float*)d_in[4];
    const float* W0f = (const float*)d_in[5];
    const float* a0f = (const float*)d_in[6];
    const float* g0  = (const float*)d_in[7];
    const float* b0  = (const float*)d_in[8];
    const float* W1s = (const float*)d_in[9];
    const float* a1s = (const float*)d_in[10];
    const float* W1f = (const float*)d_in[11];
    const float* a1f = (const float*)d_in[12];
    const float* g1  = (const float*)d_in[13];
    const float* b1  = (const float*)d_in[14];
    const int E = in_sizes[1] / 2;  // 262144

    // workspace bump allocator (~37 MB)
    char* ws = (char*)d_ws;
    auto alloc = [&](size_t bytes) {
        char* p = ws;
        ws += (bytes + 255) & ~(size_t)255;
        return p;
    };
    int* cnt2 = (int*)alloc((size_t)2 * NN * sizeof(int));
    int* rp2  = (int*)alloc((size_t)2 * (NN + 1) * sizeof(int));
    int* cur2 = (int*)alloc((size_t)2 * NN * sizeof(int));
    int* col2 = (int*)alloc((size_t)2 * E * sizeof(int));
    unsigned short* h_s = (unsigned short*)alloc((size_t)NT * HH * sizeof(unsigned short));
    unsigned short* h_f = (unsigned short*)alloc((size_t)NT * HH * sizeof(unsigned short));
    float* sc_s = (float*)alloc((size_t)NT * sizeof(float));
    float* sc_f = (float*)alloc((size_t)NT * sizeof(float));
    float* x_mid = (float*)alloc((size_t)NT * HH * sizeof(float));

    const int* rp_s = rp2;
    const int* rp_f = rp2 + (NN + 1);
    const int* col_s = col2;
    const int* col_f = col2 + E;

    const int EB = (E + 255) / 256;

    // CSR build (both edge sets in each launch)
    zero_kernel<<<(2 * NN) / 256, 256, 0, stream>>>(cnt2, 2 * NN);
    hist2_kernel<<<2 * EB, 256, 0, stream>>>(ei_s + E, ei_f + E, cnt2, E);
    scan2_kernel<<<2, 1024, 0, stream>>>(cnt2, rp2, cur2);
    scatter2_kernel<<<2 * EB, 256, 0, stream>>>(ei_s, ei_f, cur2, col2, E);

    // layer 0
    transform2_kernel<<<NT / 128, 256, 0, stream>>>(
        (const float4*)pred, W0s, a0s, W0f, a0f, h_s, sc_s, h_f, sc_f);
    aggregate_kernel<<<NN / 4, 256, 0, stream>>>(
        (const float4*)pred, (const ushort4*)h_s, sc_s, rp_s, col_s,
        (const ushort4*)h_f, sc_f, rp_f, col_f,
        (const float4*)g0, (const float4*)b0, (float4*)x_mid);

    // layer 1
    transform2_kernel<<<NT / 128, 256, 0, stream>>>(
        (const float4*)x_mid, W1s, a1s, W1f, a1f, h_s, sc_s, h_f, sc_f);
    aggregate_kernel<<<NN / 4, 256, 0, stream>>>(
        (const float4*)x_mid, (const ushort4*)h_s, sc_s, rp_s, col_s,
        (const ushort4*)h_f, sc_f, rp_f, col_f,
        (const float4*)g1, (const float4*)b1, (float4*)d_out);
}

// Round 7
// 253.983 us; speedup vs baseline: 1.4572x; 1.0081x over previous
//
#include <hip/hip_runtime.h>
#include <hip/hip_bf16.h>

#define NN 16384
#define TT 4
#define HH 64
#define NT (NN * TT)
#define NEG_SLOPE 0.2f
#define LN_EPS 1e-5f

typedef __attribute__((ext_vector_type(8))) short short8;   // 8 bf16 (4 VGPRs)
typedef __attribute__((ext_vector_type(4))) float f32x4;    // MFMA accumulator

__device__ __forceinline__ float bf2f(unsigned short u) {
    return __uint_as_float((unsigned)u << 16);
}
// f32 -> bf16 RNE, layout-independent
__device__ __forceinline__ unsigned short f2bf(float f) {
    unsigned u = __float_as_uint(f);
    return (unsigned short)((u + 0x7FFF + ((u >> 16) & 1)) >> 16);
}

// ---------------- CSR build (both edge sets fused) ----------------

__global__ void zero_kernel(int* __restrict__ a, int n) {
    int i = blockIdx.x * blockDim.x + threadIdx.x;
    if (i < n) a[i] = 0;
}

__global__ void hist2_kernel(const int* __restrict__ dst_s, const int* __restrict__ dst_f,
                             int* __restrict__ cnt2, int E) {
    int e = blockIdx.x * blockDim.x + threadIdx.x;
    if (e < E) {
        atomicAdd(&cnt2[dst_s[e]], 1);
    } else {
        e -= E;
        if (e < E) atomicAdd(&cnt2[NN + dst_f[e]], 1);
    }
}

// --- fully parallel 3-phase exclusive scan of cnt2 (2 sets x NN) ---
// A: 128 blocks x 256 -> partial[128] (block sums)
__global__ __launch_bounds__(256) void scanA_kernel(const int* __restrict__ cnt2,
                                                    int* __restrict__ partial) {
    __shared__ int wsum[4];
    const int lane = threadIdx.x & 63;
    const int wv = threadIdx.x >> 6;
    int v = cnt2[blockIdx.x * 256 + threadIdx.x];
#pragma unroll
    for (int off = 32; off > 0; off >>= 1) v += __shfl_xor(v, off, 64);
    if (lane == 0) wsum[wv] = v;
    __syncthreads();
    if (threadIdx.x == 0)
        partial[blockIdx.x] = wsum[0] + wsum[1] + wsum[2] + wsum[3];
}

// B: 1 block x 128: per-set (64 partials each) exclusive scan in place
__global__ __launch_bounds__(128) void scanB_kernel(int* __restrict__ partial) {
    const int lane = threadIdx.x & 63;
    int v = partial[threadIdx.x];
    int inc = v;
#pragma unroll
    for (int off = 1; off < 64; off <<= 1) {
        int t = __shfl_up(inc, off, 64);
        if (lane >= off) inc += t;
    }
    partial[threadIdx.x] = inc - v;  // exclusive within the set's 64 partials
}

// C: 128 blocks x 256: block-local exclusive scan + partial offset -> rp, cur
__global__ __launch_bounds__(256) void scanC_kernel(const int* __restrict__ cnt2,
                                                    const int* __restrict__ partial,
                                                    int* __restrict__ rp2,
                                                    int* __restrict__ cur2) {
    __shared__ int wsum[4];
    const int lane = threadIdx.x & 63;
    const int wv = threadIdx.x >> 6;
    const int gidx = blockIdx.x * 256 + threadIdx.x;  // index into cnt2 [0, 2*NN)
    const int set = gidx >> 14;                       // /NN
    const int i = gidx & (NN - 1);
    int v = cnt2[gidx];
    int inc = v;
#pragma unroll
    for (int off = 1; off < 64; off <<= 1) {
        int t = __shfl_up(inc, off, 64);
        if (lane >= off) inc += t;
    }
    if (lane == 63) wsum[wv] = inc;
    __syncthreads();
    int wbase = 0;
#pragma unroll
    for (int w = 0; w < 4; w++)
        if (w < wv) wbase += wsum[w];
    int excl = (inc - v) + wbase + partial[blockIdx.x];
    int* rp = rp2 + set * (NN + 1);
    rp[i] = excl;
    cur2[gidx] = excl;
    if (i == NN - 1) rp[NN] = excl + v;  // set total
}

__global__ void scatter2_kernel(const int* __restrict__ ei_s, const int* __restrict__ ei_f,
                                int* __restrict__ cur2, int* __restrict__ col2, int E) {
    int e = blockIdx.x * blockDim.x + threadIdx.x;
    if (e < E) {
        int d = ei_s[E + e];
        int pos = atomicAdd(&cur2[d], 1);
        col2[pos] = ei_s[e];
    } else {
        e -= E;
        if (e < E) {
            int d = ei_f[E + e];
            int pos = atomicAdd(&cur2[NN + d], 1);
            col2[E + pos] = ei_f[e];
        }
    }
}

// ------- fused dual transform via MFMA: h_s = x*Ws, h_f = x*Wf + scores ------
// v_mfma_f32_16x16x32_bf16. A-frag: A[m=lane&15][k=quad*8+j]. B-frag (KxN):
// B[k=quad*8+j][n=lane&15]. C/D: col=lane&15, row=quad*4+reg.
// Wave = 32 rows (2 row-tiles); block = 4 waves = 128 rows; grid = NT/128.

__global__ __launch_bounds__(256) void transform2_kernel(
    const float4* __restrict__ x4,
    const float* __restrict__ Ws, const float* __restrict__ as_,
    const float* __restrict__ Wf, const float* __restrict__ af,
    unsigned short* __restrict__ h_s, float* __restrict__ sc_s,
    unsigned short* __restrict__ h_f, float* __restrict__ sc_f) {
    const int lane = threadIdx.x & 63;
    const int wv = threadIdx.x >> 6;
    const int m = lane & 15;
    const int quad = lane >> 4;

    short8 Bs[4][2], Bf[4][2];
#pragma unroll
    for (int c = 0; c < 4; c++) {
#pragma unroll
        for (int ks = 0; ks < 2; ks++) {
#pragma unroll
            for (int j = 0; j < 8; j++) {
                int k = ks * 32 + quad * 8 + j;
                int n = c * 16 + m;
                Bs[c][ks][j] = (short)f2bf(Ws[k * 64 + n]);
                Bf[c][ks][j] = (short)f2bf(Wf[k * 64 + n]);
            }
        }
    }
    float a_s[4], a_f[4];
#pragma unroll
    for (int c = 0; c < 4; c++) { a_s[c] = as_[c * 16 + m]; a_f[c] = af[c * 16 + m]; }

    const int rowbase = blockIdx.x * 128 + wv * 32;
#pragma unroll
    for (int rt = 0; rt < 2; rt++) {
        const int row0 = rowbase + rt * 16;
        const long xbase = (long)(row0 + m) * 16 + quad * 2;
        float4 xa = x4[xbase];
        float4 xb = x4[xbase + 1];
        float4 xc = x4[xbase + 8];
        float4 xd = x4[xbase + 9];
        short8 A0, A1;
        A0[0] = (short)f2bf(xa.x); A0[1] = (short)f2bf(xa.y);
        A0[2] = (short)f2bf(xa.z); A0[3] = (short)f2bf(xa.w);
        A0[4] = (short)f2bf(xb.x); A0[5] = (short)f2bf(xb.y);
        A0[6] = (short)f2bf(xb.z); A0[7] = (short)f2bf(xb.w);
        A1[0] = (short)f2bf(xc.x); A1[1] = (short)f2bf(xc.y);
        A1[2] = (short)f2bf(xc.z); A1[3] = (short)f2bf(xc.w);
        A1[4] = (short)f2bf(xd.x); A1[5] = (short)f2bf(xd.y);
        A1[6] = (short)f2bf(xd.z); A1[7] = (short)f2bf(xd.w);

        f32x4 accs[4], accf[4];
#pragma unroll
        for (int c = 0; c < 4; c++) {
            accs[c] = (f32x4){0.f, 0.f, 0.f, 0.f};
            accf[c] = (f32x4){0.f, 0.f, 0.f, 0.f};
        }
#pragma unroll
        for (int c = 0; c < 4; c++) {
            accs[c] = __builtin_amdgcn_mfma_f32_16x16x32_bf16(A0, Bs[c][0], accs[c], 0, 0, 0);
            accs[c] = __builtin_amdgcn_mfma_f32_16x16x32_bf16(A1, Bs[c][1], accs[c], 0, 0, 0);
            accf[c] = __builtin_amdgcn_mfma_f32_16x16x32_bf16(A0, Bf[c][0], accf[c], 0, 0, 0);
            accf[c] = __builtin_amdgcn_mfma_f32_16x16x32_bf16(A1, Bf[c][1], accf[c], 0, 0, 0);
        }
#pragma unroll
        for (int reg = 0; reg < 4; reg++) {
            const int row = row0 + quad * 4 + reg;
            float ps = 0.f, pf = 0.f;
#pragma unroll
            for (int c = 0; c < 4; c++) {
                h_s[(long)row * 64 + c * 16 + m] = f2bf(accs[c][reg]);
                h_f[(long)row * 64 + c * 16 + m] = f2bf(accf[c][reg]);
                ps = fmaf(accs[c][reg], a_s[c], ps);
                pf = fmaf(accf[c][reg], a_f[c], pf);
            }
#pragma unroll
            for (int off = 1; off < 16; off <<= 1) {
                ps += __shfl_xor(ps, off, 64);
                pf += __shfl_xor(pf, off, 64);
            }
            if (m == 0) {
                sc_s[row] = (ps > 0.f) ? ps : NEG_SLOPE * ps;  // LeakyReLU folded in
                sc_f[row] = (pf > 0.f) ? pf : NEG_SLOPE * pf;
            }
        }
    }
}

// ---------------- attention aggregation ----------------
// wave per (node, edge-set): 4 waves/block = 2 nodes. Set-f wave deposits its
// message in LDS; set-s wave does residual + LN + store. Halves the serial
// edge chain per wave and doubles gather TLP.
// lane: t = lane>>4, channels 4*(lane&15)..+3. Single-pass softmax (logits
// O(+-8): no overflow; identical to max-subtracted form).

__device__ __forceinline__ void agg_set(const ushort4* __restrict__ h4,
                                        const float* __restrict__ sc,
                                        const int* __restrict__ rp,
                                        const int* __restrict__ col,
                                        int n, int t, int lane, float4& msg) {
    const int beg = rp[n], end = rp[n + 1];
    float den = 0.f;
    float ax = 0.f, ay = 0.f, az = 0.f, aw = 0.f;
    int j = beg;
    for (; j + 8 <= end; j += 8) {
        int s[8];
        float l[8];
        ushort4 hh[8];
#pragma unroll
        for (int u = 0; u < 8; u++) s[u] = col[j + u];
#pragma unroll
        for (int u = 0; u < 8; u++) l[u] = sc[s[u] * 4 + t];
#pragma unroll
        for (int u = 0; u < 8; u++) hh[u] = h4[s[u] * 64 + lane];
#pragma unroll
        for (int u = 0; u < 8; u++) {
            float e = __expf(l[u]);
            den += e;
            ax = fmaf(e, bf2f(hh[u].x), ax);
            ay = fmaf(e, bf2f(hh[u].y), ay);
            az = fmaf(e, bf2f(hh[u].z), az);
            aw = fmaf(e, bf2f(hh[u].w), aw);
        }
    }
    for (; j + 4 <= end; j += 4) {
        int s[4];
        float l[4];
        ushort4 hh[4];
#pragma unroll
        for (int u = 0; u < 4; u++) s[u] = col[j + u];
#pragma unroll
        for (int u = 0; u < 4; u++) l[u] = sc[s[u] * 4 + t];
#pragma unroll
        for (int u = 0; u < 4; u++) hh[u] = h4[s[u] * 64 + lane];
#pragma unroll
        for (int u = 0; u < 4; u++) {
            float e = __expf(l[u]);
            den += e;
            ax = fmaf(e, bf2f(hh[u].x), ax);
            ay = fmaf(e, bf2f(hh[u].y), ay);
            az = fmaf(e, bf2f(hh[u].z), az);
            aw = fmaf(e, bf2f(hh[u].w), aw);
        }
    }
    for (; j < end; j++) {
        int s0 = col[j];
        float l0 = sc[s0 * 4 + t];
        ushort4 h0 = h4[s0 * 64 + lane];
        float e0 = __expf(l0);
        den += e0;
        ax = fmaf(e0, bf2f(h0.x), ax);
        ay = fmaf(e0, bf2f(h0.y), ay);
        az = fmaf(e0, bf2f(h0.z), az);
        aw = fmaf(e0, bf2f(h0.w), aw);
    }
    if (end > beg) {
        float r = 1.f / den;
        msg.x = ax * r; msg.y = ay * r; msg.z = az * r; msg.w = aw * r;
    } else {
        msg.x = msg.y = msg.z = msg.w = 0.f;
    }
}

__global__ __launch_bounds__(256) void aggregate_kernel(
    const float4* __restrict__ x4,
    const ushort4* __restrict__ hs4, const float* __restrict__ scs,
    const int* __restrict__ rps, const int* __restrict__ cols,
    const ushort4* __restrict__ hf4, const float* __restrict__ scf,
    const int* __restrict__ rpf, const int* __restrict__ colf,
    const float4* __restrict__ g4, const float4* __restrict__ b4,
    float4* __restrict__ out4) {
    __shared__ float4 msgF[2][64];
    const int wv = threadIdx.x >> 6;
    const int lane = threadIdx.x & 63;
    const int slot = wv >> 1;                  // node slot in block (0/1)
    const int set = wv & 1;                    // 0 = structural, 1 = functional
    const int n = blockIdx.x * 2 + slot;
    const int t = lane >> 4;
    const int ci = lane & 15;

    float4 msg;
    if (set == 0) {
        agg_set(hs4, scs, rps, cols, n, t, lane, msg);
    } else {
        agg_set(hf4, scf, rpf, colf, n, t, lane, msg);
        msgF[slot][lane] = msg;
    }
    __syncthreads();
    if (set == 1) return;

    float4 mf = msgF[slot][lane];
    float4 xv = x4[n * 64 + lane];  // x[n][t][4*ci..+3]

    float v0 = xv.x + 0.5f * (msg.x + mf.x);
    float v1 = xv.y + 0.5f * (msg.y + mf.y);
    float v2 = xv.z + 0.5f * (msg.z + mf.z);
    float v3 = xv.w + 0.5f * (msg.w + mf.w);

    // LayerNorm over H=64: 16-lane group (same t), 4 values/lane
    float sum = (v0 + v1) + (v2 + v3);
#pragma unroll
    for (int off = 1; off < 16; off <<= 1) sum += __shfl_xor(sum, off, 64);
    float mu = sum * (1.f / 64.f);
    float d0 = v0 - mu, d1 = v1 - mu, d2 = v2 - mu, d3 = v3 - mu;
    float var = (d0 * d0 + d1 * d1) + (d2 * d2 + d3 * d3);
#pragma unroll
    for (int off = 1; off < 16; off <<= 1) var += __shfl_xor(var, off, 64);
    var *= (1.f / 64.f);
    float inv = rsqrtf(var + LN_EPS);
    float4 gv = g4[ci], bv = b4[ci];
    float4 o;
    o.x = d0 * inv * gv.x + bv.x;
    o.y = d1 * inv * gv.y + bv.y;
    o.z = d2 * inv * gv.z + bv.z;
    o.w = d3 * inv * gv.w + bv.w;
    out4[n * 64 + lane] = o;
}

// ---------------- launch ----------------

extern "C" void kernel_launch(void* const* d_in, const int* in_sizes, int n_in,
                              void* d_out, int out_size, void* d_ws, size_t ws_size,
                              hipStream_t stream) {
    const float* pred = (const float*)d_in[0];
    const int* ei_s = (const int*)d_in[1];
    const int* ei_f = (const int*)d_in[2];
    const float* W0s = (const float*)d_in[3];
    const float* a0s = (const float*)d_in[4];
    const float* W0f = (const float*)d_in[5];
    const float* a0f = (const float*)d_in[6];
    const float* g0  = (const float*)d_in[7];
    const float* b0  = (const float*)d_in[8];
    const float* W1s = (const float*)d_in[9];
    const float* a1s = (const float*)d_in[10];
    const float* W1f = (const float*)d_in[11];
    const float* a1f = (const float*)d_in[12];
    const float* g1  = (const float*)d_in[13];
    const float* b1  = (const float*)d_in[14];
    const int E = in_sizes[1] / 2;  // 262144

    // workspace bump allocator (~37 MB)
    char* ws = (char*)d_ws;
    auto alloc = [&](size_t bytes) {
        char* p = ws;
        ws += (bytes + 255) & ~(size_t)255;
        return p;
    };
    int* cnt2 = (int*)alloc((size_t)2 * NN * sizeof(int));
    int* rp2  = (int*)alloc((size_t)2 * (NN + 1) * sizeof(int));
    int* cur2 = (int*)alloc((size_t)2 * NN * sizeof(int));
    int* col2 = (int*)alloc((size_t)2 * E * sizeof(int));
    int* partial = (int*)alloc(128 * sizeof(int));
    unsigned short* h_s = (unsigned short*)alloc((size_t)NT * HH * sizeof(unsigned short));
    unsigned short* h_f = (unsigned short*)alloc((size_t)NT * HH * sizeof(unsigned short));
    float* sc_s = (float*)alloc((size_t)NT * sizeof(float));
    float* sc_f = (float*)alloc((size_t)NT * sizeof(float));
    float* x_mid = (float*)alloc((size_t)NT * HH * sizeof(float));

    const int* rp_s = rp2;
    const int* rp_f = rp2 + (NN + 1);
    const int* col_s = col2;
    const int* col_f = col2 + E;

    const int EB = (E + 255) / 256;

    // CSR build (both edge sets in each launch)
    zero_kernel<<<(2 * NN) / 256, 256, 0, stream>>>(cnt2, 2 * NN);
    hist2_kernel<<<2 * EB, 256, 0, stream>>>(ei_s + E, ei_f + E, cnt2, E);
    scanA_kernel<<<128, 256, 0, stream>>>(cnt2, partial);
    scanB_kernel<<<1, 128, 0, stream>>>(partial);
    scanC_kernel<<<128, 256, 0, stream>>>(cnt2, partial, rp2, cur2);
    scatter2_kernel<<<2 * EB, 256, 0, stream>>>(ei_s, ei_f, cur2, col2, E);

    // layer 0
    transform2_kernel<<<NT / 128, 256, 0, stream>>>(
        (const float4*)pred, W0s, a0s, W0f, a0f, h_s, sc_s, h_f, sc_f);
    aggregate_kernel<<<NN / 2, 256, 0, stream>>>(
        (const float4*)pred, (const ushort4*)h_s, sc_s, rp_s, col_s,
        (const ushort4*)h_f, sc_f, rp_f, col_f,
        (const float4*)g0, (const float4*)b0, (float4*)x_mid);

    // layer 1
    transform2_kernel<<<NT / 128, 256, 0, stream>>>(
        (const float4*)x_mid, W1s, a1s, W1f, a1f, h_s, sc_s, h_f, sc_f);
    aggregate_kernel<<<NN / 2, 256, 0, stream>>>(
        (const float4*)x_mid, (const ushort4*)h_s, sc_s, rp_s, col_s,
        (const ushort4*)h_f, sc_f, rp_f, col_f,
        (const float4*)g1, (const float4*)b1, (float4*)d_out);
}